// Round 6
// baseline (108.521 us; speedup 1.0000x reference)
//
#include <hip/hip_runtime.h>

#define H_    128
#define W_    128
#define C_    256
#define PLANE (H_*W_)
#define ND    9
#define NDISP 81
#define TILE  8
#define HALO  4
#define KC    32
#define NSTEP 8
#define NT    10     // band: key rows 2w .. 2w+9 per wave
#define SROW  170    // floats per query in sS: 10 rows x 17

typedef __attribute__((ext_vector_type(8))) short short8;
typedef __attribute__((ext_vector_type(4))) float f32x4;

__device__ __forceinline__ unsigned cvtpk(float lo, float hi) {
    unsigned r;
    asm("v_cvt_pk_bf16_f32 %0, %1, %2" : "=v"(r) : "v"(lo), "v"(hi));
    return r;
}

__global__ __launch_bounds__(256, 4) void corr_mfma(
    const float* __restrict__ first, const float* __restrict__ second,
    float* __restrict__ out)
{
    __shared__ float sS[2][16 * SROW];   // 21.8 KB, epilogue only

    const int tid  = threadIdx.x;
    const int lane = tid & 63;
    const int wv   = tid >> 6;

    // XCD-aware swizzle: 128 consecutive tiles (half an image) per XCD
    const int bid  = blockIdx.x;
    const int tile = (bid & 7) * 128 + (bid >> 3);
    const int b  = tile >> 8;
    const int by = (tile >> 4) & 15;
    const int bx = tile & 15;
    const int x0 = bx * TILE, y0 = by * TILE;

    const float* fB = first  + (size_t)b * C_ * PLANE;
    const float* sB = second + (size_t)b * C_ * PLANE;

    // ---- per-lane constants ----
    const int g   = lane >> 4;        // MFMA k-group -> channels 8g..8g+7
    const int kxq = lane & 15;        // B-frag key col / A-frag query idx

    // Q: lane owns (query q = 16*wv + kxq, channel group g)
    const int q  = 16 * wv + kxq;
    const int qy = q >> 3, qx = q & 7;
    const float* qsrc = fB + (size_t)g * 8 * PLANE + (y0 + qy) * W_ + (x0 + qx);

    // K row-base pointers (x and y clamped; invalid keys give garbage that the
    // epilogue masks to zero)
    const int xk = min(max(x0 - HALO + kxq, 0), W_ - 1);
    const float* rowp[NT];
    #pragma unroll
    for (int nt = 0; nt < NT; ++nt) {
        const int ry = min(max(y0 - HALO + 2 * wv + nt, 0), H_ - 1);
        rowp[nt] = sB + (size_t)g * 8 * PLANE + ry * W_ + xk;
    }

    f32x4 acc[NT];
    #pragma unroll
    for (int i = 0; i < NT; ++i) acc[i] = (f32x4){0.f, 0.f, 0.f, 0.f};

    // ---- main loop: barrier-free, register-direct ----
    #pragma unroll 1
    for (int s = 0; s < NSTEP; ++s) {
        const size_t co = (size_t)s * KC * PLANE;

        float qv[8];
        #pragma unroll
        for (int j = 0; j < 8; ++j) qv[j] = qsrc[co + (size_t)j * PLANE];
        unsigned a0 = cvtpk(qv[0], qv[1]), a1 = cvtpk(qv[2], qv[3]);
        unsigned a2 = cvtpk(qv[4], qv[5]), a3 = cvtpk(qv[6], qv[7]);
        union { unsigned u[4]; short8 v; } ua = {{a0, a1, a2, a3}};

        #pragma unroll
        for (int nt = 0; nt < NT; ++nt) {
            float bj[8];
            #pragma unroll
            for (int j = 0; j < 8; ++j)
                bj[j] = rowp[nt][co + (size_t)j * PLANE];
            unsigned b0 = cvtpk(bj[0], bj[1]);
            unsigned b1 = cvtpk(bj[2], bj[3]);
            unsigned b2 = cvtpk(bj[4], bj[5]);
            unsigned b3 = cvtpk(bj[6], bj[7]);
            union { unsigned u[4]; short8 v; } ub = {{b0, b1, b2, b3}};
            acc[nt] = __builtin_amdgcn_mfma_f32_16x16x32_bf16(ua.v, ub.v, acc[nt], 0, 0, 0);
        }
    }

    // ---- epilogue: 2 rounds x 2 waves dump band-S, all threads gather ----
    const float scale = 1.0f / (float)C_;
    #pragma unroll
    for (int round = 0; round < 2; ++round) {
        __syncthreads();
        if ((wv >> 1) == round) {
            float* dst = sS[wv & 1];
            #pragma unroll
            for (int nt = 0; nt < NT; ++nt) {
                #pragma unroll
                for (int r = 0; r < 4; ++r) {
                    const int qi = (lane >> 4) * 4 + r;
                    dst[qi * SROW + nt * 17 + kxq] = acc[nt][r];
                }
            }
        }
        __syncthreads();
        for (int idx = tid; idx < 2 * 16 * NDISP; idx += 256) {
            const int d   = idx >> 5;
            const int qq  = idx & 31;
            const int pp2 = qq >> 4;
            const int qi  = qq & 15;
            const int dy = d / ND, dx = d % ND;
            const int wv2 = round * 2 + pp2;
            const int gqy = 2 * wv2 + (qi >> 3);
            const int gqx = qi & 7;
            const int lr  = (qi >> 3) + dy;
            const int col = gqx + dx;
            const int kyg = y0 + gqy - HALO + dy;
            const int kxg = x0 + gqx - HALO + dx;
            float v = 0.f;
            if ((unsigned)kyg < (unsigned)H_ && (unsigned)kxg < (unsigned)W_)
                v = sS[pp2][qi * SROW + lr * 17 + col] * scale;
            out[((size_t)b * NDISP + d) * PLANE + (size_t)(y0 + gqy) * W_ + (x0 + gqx)] = v;
        }
    }
}

extern "C" void kernel_launch(void* const* d_in, const int* in_sizes, int n_in,
                              void* d_out, int out_size, void* d_ws, size_t ws_size,
                              hipStream_t stream) {
    const float* first  = (const float*)d_in[0];
    const float* second = (const float*)d_in[1];
    float* out = (float*)d_out;

    dim3 grid(1024);
    dim3 block(256);
    corr_mfma<<<grid, block, 0, stream>>>(first, second, out);
}

// Round 8
// 66.646 us; speedup vs baseline: 1.6283x; 1.6283x over previous
//
#include <hip/hip_runtime.h>

#define H_    128
#define W_    128
#define C_    256
#define PLANE (H_*W_)
#define ND    9
#define NDISP 81
#define TILE  8
#define HALO  4
#define KC    32
#define NSTEP 8
#define NT    10     // band: key rows 2w .. 2w+9 per wave
#define KPSTR 260    // u32 per pair-plane (256 px + 4 pad)
#define SROW  170    // floats per query in sS: 10 rows x 17

typedef __attribute__((ext_vector_type(8))) short short8;
typedef __attribute__((ext_vector_type(4))) float f32x4;
typedef __attribute__((ext_vector_type(4))) unsigned u32x4;

union SharedU {
    unsigned kbuf[16 * KPSTR];   // 16.6 KB  [pair][px] packed bf16x2 K tile
    float sS[2][16 * SROW];      // 21.8 KB  epilogue scratch
};

__device__ __forceinline__ unsigned cvtpk(float lo, float hi) {
    unsigned r;
    asm("v_cvt_pk_bf16_f32 %0, %1, %2" : "=v"(r) : "v"(lo), "v"(hi));
    return r;
}

// pinned global loads; asm base must be wave-uniform (SGPR), all per-lane
// terms live in the 32-bit voffset
#define STAGE_K(C0) do {                                                      \
    const unsigned long long kb_ =                                            \
        (unsigned long long)(sB + (size_t)(C0) * PLANE);                      \
    _Pragma("unroll")                                                         \
    for (int j = 0; j < 8; ++j)                                               \
        asm volatile("global_load_dwordx4 %0, %1, %2"                         \
                     : "=v"(kf[j]) : "v"(vkw[j]), "s"(kb_) : "memory");       \
} while (0)

#define STAGE_Q(C0) do {                                                      \
    const unsigned long long qb_ =                                            \
        (unsigned long long)(fB + (size_t)(C0) * PLANE);                      \
    _Pragma("unroll")                                                         \
    for (int j = 0; j < 8; ++j)                                               \
        asm volatile("global_load_dword %0, %1, %2"                           \
                     : "=v"(qf[j])                                            \
                     : "v"(vq + (unsigned)(j * PLANE * 4)), "s"(qb_)          \
                     : "memory");                                             \
} while (0)

__global__ __launch_bounds__(256, 4) void corr_mfma(
    const float* __restrict__ first, const float* __restrict__ second,
    float* __restrict__ out)
{
    __shared__ SharedU sh;

    const int tid  = threadIdx.x;
    const int lane = tid & 63;
    const int wv   = tid >> 6;

    // XCD-aware swizzle: 128 consecutive tiles (half an image) per XCD
    const int bid  = blockIdx.x;
    const int tile = (bid & 7) * 128 + (bid >> 3);
    const int b  = tile >> 8;
    const int by = (tile >> 4) & 15;
    const int bx = tile & 15;
    const int x0 = bx * TILE, y0 = by * TILE;

    const float* fB = first  + (size_t)b * C_ * PLANE;
    const float* sB = second + (size_t)b * C_ * PLANE;

    // ---- per-lane constants ----
    const int g   = lane >> 4;        // MFMA k-group -> channels 8g..8g+7
    const int kxq = lane & 15;        // B-frag key col / A-frag query idx

    // K staging: lane covers px 4l..4l+3 -> halo row l>>2, col 4(l&3); clamped
    const int krow = lane >> 2;
    const int kcol = (lane & 3) * 4;
    const int gyc  = min(max(y0 - HALO + krow, 0), H_ - 1);
    const int gxc  = min(max(x0 - HALO + kcol, 0), W_ - 4);
    // per-lane byte voffsets for the 8 channel planes this wave stages
    unsigned vkw[8];
    #pragma unroll
    for (int j = 0; j < 8; ++j)
        vkw[j] = (unsigned)((((8 * wv + j) * PLANE) + gyc * W_ + gxc) * 4);

    // Q: lane owns (query q = 16*wv + kxq, channel group g)
    const int q  = 16 * wv + kxq;
    const int qy = q >> 3, qx = q & 7;
    const unsigned vq = (unsigned)((g * 8 * PLANE + (y0 + qy) * W_ + (x0 + qx)) * 4);

    f32x4 acc[NT];
    #pragma unroll
    for (int i = 0; i < NT; ++i) acc[i] = (f32x4){0.f, 0.f, 0.f, 0.f};

    f32x4 kf[8];
    float qf[8];

    // prologue: stage step 0
    STAGE_K(0);
    STAGE_Q(0);

    // B-fragment base: dword index (4g)*KPSTR + kxq
    const unsigned* kbl = sh.kbuf + (4 * g) * KPSTR + kxq;

    #pragma unroll 1
    for (int s = 0; s < NSTEP; ++s) {
        asm volatile("s_waitcnt vmcnt(0)" ::: "memory");  // step-s regs landed
        __syncthreads();                                  // kbuf free to overwrite
        __builtin_amdgcn_sched_barrier(0);

        // pack + write K tile: pair j2 = channels (2j2, 2j2+1) of this wave
        #pragma unroll
        for (int j2 = 0; j2 < 4; ++j2) {
            u32x4 w;
            #pragma unroll
            for (int k = 0; k < 4; ++k)
                w[k] = cvtpk(kf[2 * j2][k], kf[2 * j2 + 1][k]);
            *reinterpret_cast<u32x4*>(
                &sh.kbuf[(4 * wv + j2) * KPSTR + 4 * lane]) = w;
        }
        // A-fragment from Q registers (consumed before qf overwrite)
        union { unsigned u[4]; short8 v; } ua;
        ua.u[0] = cvtpk(qf[0], qf[1]); ua.u[1] = cvtpk(qf[2], qf[3]);
        ua.u[2] = cvtpk(qf[4], qf[5]); ua.u[3] = cvtpk(qf[6], qf[7]);

        __syncthreads();                                  // kbuf ready
        __builtin_amdgcn_sched_barrier(0);

        if (s < NSTEP - 1) {   // issue step s+1 loads; latency hides under compute
            STAGE_K((s + 1) * KC);
            STAGE_Q((s + 1) * KC);
        }

        __builtin_amdgcn_s_setprio(1);
        #pragma unroll
        for (int nt = 0; nt < NT; ++nt) {
            const unsigned* pb = kbl + (2 * wv + nt) * 16;
            union { unsigned u[4]; short8 v; } ub;
            #pragma unroll
            for (int j = 0; j < 4; ++j)
                ub.u[j] = pb[j * KPSTR];
            acc[nt] = __builtin_amdgcn_mfma_f32_16x16x32_bf16(ua.v, ub.v, acc[nt], 0, 0, 0);
        }
        __builtin_amdgcn_s_setprio(0);
    }

    // ---- epilogue: 2 rounds x 2 waves dump band-S, all threads gather ----
    const float scale = 1.0f / (float)C_;
    #pragma unroll
    for (int round = 0; round < 2; ++round) {
        __syncthreads();
        if ((wv >> 1) == round) {
            float* dst = sh.sS[wv & 1];
            #pragma unroll
            for (int nt = 0; nt < NT; ++nt) {
                #pragma unroll
                for (int r = 0; r < 4; ++r) {
                    const int qi = (lane >> 4) * 4 + r;
                    dst[qi * SROW + nt * 17 + kxq] = acc[nt][r];
                }
            }
        }
        __syncthreads();
        for (int idx = tid; idx < 2 * 16 * NDISP; idx += 256) {
            const int d   = idx >> 5;
            const int qq  = idx & 31;
            const int pp2 = qq >> 4;
            const int qi  = qq & 15;
            const int dy = d / ND, dx = d % ND;
            const int wv2 = round * 2 + pp2;
            const int gqy = 2 * wv2 + (qi >> 3);
            const int gqx = qi & 7;
            const int lr  = (qi >> 3) + dy;
            const int col = gqx + dx;
            const int kyg = y0 + gqy - HALO + dy;
            const int kxg = x0 + gqx - HALO + dx;
            float v = 0.f;
            if ((unsigned)kyg < (unsigned)H_ && (unsigned)kxg < (unsigned)W_)
                v = sh.sS[pp2][qi * SROW + lr * 17 + col] * scale;
            out[((size_t)b * NDISP + d) * PLANE + (size_t)(y0 + gqy) * W_ + (x0 + gqx)] = v;
        }
    }
}

extern "C" void kernel_launch(void* const* d_in, const int* in_sizes, int n_in,
                              void* d_out, int out_size, void* d_ws, size_t ws_size,
                              hipStream_t stream) {
    const float* first  = (const float*)d_in[0];
    const float* second = (const float*)d_in[1];
    float* out = (float*)d_out;

    dim3 grid(1024);
    dim3 block(256);
    corr_mfma<<<grid, block, 0, stream>>>(first, second, out);
}

// Round 11
// 61.736 us; speedup vs baseline: 1.7578x; 1.0795x over previous
//
#include <hip/hip_runtime.h>

#define H_    128
#define W_    128
#define C_    256
#define PLANE (H_*W_)
#define ND    9
#define NDISP 81
#define TILE  8
#define HALO  4
#define KC    32
#define NSTEP 8
#define NT    10     // band: key rows 2w .. 2w+9 per wave
#define KPSTR 260    // u32 per pair-plane (256 px + 4 pad)
#define SROW  170    // floats per query in sS: 10 rows x 17
#define SLAB  (KC * PLANE * 4)   // bytes per 32-channel slab (2 MB)

typedef __attribute__((ext_vector_type(8))) short short8;
typedef __attribute__((ext_vector_type(4))) float f32x4;
typedef __attribute__((ext_vector_type(4))) unsigned u32x4;

union SharedU {
    unsigned kbuf[2][16 * KPSTR];   // 33.3 KB double-buffered packed K tile
    float sS[2][16 * SROW];         // 21.8 KB epilogue scratch (overlays)
};

__device__ __forceinline__ unsigned cvtpk(float lo, float hi) {
    unsigned r;
    asm("v_cvt_pk_bf16_f32 %0, %1, %2" : "=v"(r) : "v"(lo), "v"(hi));
    return r;
}

// pinned global loads; SGPR base fixed, all variation in the 32-bit voffset.
// COFF = byte offset of this step's channel slab (bid-staggered, pure ALU).
#define STAGE_K(COFF) do {                                                    \
    _Pragma("unroll")                                                         \
    for (int j = 0; j < 8; ++j)                                               \
        asm volatile("global_load_dwordx4 %0, %1, %2"                         \
                     : "=v"(kf[j])                                            \
                     : "v"(vkw[j] + (COFF)), "s"(sB64) : "memory");           \
} while (0)

#define STAGE_Q(COFF) do {                                                    \
    _Pragma("unroll")                                                         \
    for (int j = 0; j < 8; ++j)                                               \
        asm volatile("global_load_dword %0, %1, %2"                           \
                     : "=v"(qf[j])                                            \
                     : "v"(vq + (unsigned)(j * PLANE * 4) + (COFF)),          \
                       "s"(fB64) : "memory");                                 \
} while (0)

__global__ __launch_bounds__(256, 4) void corr_mfma(
    const float* __restrict__ first, const float* __restrict__ second,
    float* __restrict__ out)
{
    __shared__ SharedU sh;

    const int tid  = threadIdx.x;
    const int lane = tid & 63;
    const int wv   = tid >> 6;

    // XCD-aware swizzle: 128 consecutive tiles (half an image) per XCD
    const int bid  = blockIdx.x;
    const int tile = (bid & 7) * 128 + (bid >> 3);
    const int b  = tile >> 8;
    const int by = (tile >> 4) & 15;
    const int bx = tile & 15;
    const int x0 = bx * TILE, y0 = by * TILE;

    const float* fB = first  + (size_t)b * C_ * PLANE;
    const float* sB = second + (size_t)b * C_ * PLANE;
    const unsigned long long fB64 = (unsigned long long)fB;
    const unsigned long long sB64 = (unsigned long long)sB;

    // channel-phase stagger: decorrelate blocks' per-step memory streams
    const int ph = bid & 7;

    // ---- per-lane constants ----
    const int g   = lane >> 4;        // MFMA k-group -> channels 8g..8g+7
    const int kxq = lane & 15;        // B-frag key col / A-frag query idx

    // K staging: lane covers px 4l..4l+3 -> halo row l>>2, col 4(l&3); clamped
    const int krow = lane >> 2;
    const int kcol = (lane & 3) * 4;
    const int gyc  = min(max(y0 - HALO + krow, 0), H_ - 1);
    const int gxc  = min(max(x0 - HALO + kcol, 0), W_ - 4);
    unsigned vkw[8];
    #pragma unroll
    for (int j = 0; j < 8; ++j)
        vkw[j] = (unsigned)((((8 * wv + j) * PLANE) + gyc * W_ + gxc) * 4);

    // Q: lane owns (query q = 16*wv + kxq, channel group g)
    const int q  = 16 * wv + kxq;
    const int qy = q >> 3, qx = q & 7;
    const unsigned vq = (unsigned)((g * 8 * PLANE + (y0 + qy) * W_ + (x0 + qx)) * 4);

    f32x4 acc[NT];
    #pragma unroll
    for (int i = 0; i < NT; ++i) acc[i] = (f32x4){0.f, 0.f, 0.f, 0.f};

    f32x4 kf[8];
    float qf[8];

    // prologue: stage step 0
    {
        const unsigned c0 = (unsigned)(ph * SLAB);
        STAGE_K(c0);
        STAGE_Q(c0);
    }

    #pragma unroll 1
    for (int s = 0; s < NSTEP; ++s) {
        unsigned* kb = sh.kbuf[s & 1];

        asm volatile("s_waitcnt vmcnt(0)" ::: "memory");   // step-s regs landed
        __builtin_amdgcn_sched_barrier(0);                 // rule #18: pin consumers below

        // pack K(s): pair j2 = channels (2j2, 2j2+1) of this wave
        #pragma unroll
        for (int j2 = 0; j2 < 4; ++j2) {
            u32x4 w;
            #pragma unroll
            for (int k = 0; k < 4; ++k)
                w[k] = cvtpk(kf[2 * j2][k], kf[2 * j2 + 1][k]);
            *reinterpret_cast<u32x4*>(&kb[(4 * wv + j2) * KPSTR + 4 * lane]) = w;
        }
        // A-fragment from Q registers
        union { unsigned u[4]; short8 v; } ua;
        ua.u[0] = cvtpk(qf[0], qf[1]); ua.u[1] = cvtpk(qf[2], qf[3]);
        ua.u[2] = cvtpk(qf[4], qf[5]); ua.u[3] = cvtpk(qf[6], qf[7]);
        __builtin_amdgcn_sched_barrier(0);                 // ua/pack done before reissue

        if (s < NSTEP - 1) {   // issue step s+1 BEFORE the barrier (pure-ALU offset)
            const unsigned cn = (unsigned)(((s + 1 + ph) & 7) * SLAB);
            STAGE_K(cn);
            STAGE_Q(cn);
        }

        asm volatile("s_waitcnt lgkmcnt(0)" ::: "memory"); // ds_writes visible
        __builtin_amdgcn_sched_barrier(0);
        __builtin_amdgcn_s_barrier();                      // ONLY barrier/step
        __builtin_amdgcn_sched_barrier(0);

        const unsigned* kbl = kb + (4 * g) * KPSTR + kxq;
        #pragma unroll
        for (int nt = 0; nt < NT; ++nt) {
            const unsigned* pb = kbl + (2 * wv + nt) * 16;
            union { unsigned u[4]; short8 v; } ub;
            #pragma unroll
            for (int j = 0; j < 4; ++j)
                ub.u[j] = pb[j * KPSTR];
            acc[nt] = __builtin_amdgcn_mfma_f32_16x16x32_bf16(ua.v, ub.v, acc[nt], 0, 0, 0);
        }
    }

    // ---- epilogue: 2 rounds x 2 waves dump band-S, all threads gather ----
    const float scale = 1.0f / (float)C_;
    #pragma unroll
    for (int round = 0; round < 2; ++round) {
        __syncthreads();
        if ((wv >> 1) == round) {
            float* dst = sh.sS[wv & 1];
            #pragma unroll
            for (int nt = 0; nt < NT; ++nt) {
                #pragma unroll
                for (int r = 0; r < 4; ++r) {
                    const int qi = (lane >> 4) * 4 + r;
                    dst[qi * SROW + nt * 17 + kxq] = acc[nt][r];
                }
            }
        }
        __syncthreads();
        for (int idx = tid; idx < 2 * 16 * NDISP; idx += 256) {
            const int d   = idx >> 5;
            const int qq  = idx & 31;
            const int pp2 = qq >> 4;
            const int qi  = qq & 15;
            const int dy = d / ND, dx = d % ND;
            const int wv2 = round * 2 + pp2;
            const int gqy = 2 * wv2 + (qi >> 3);
            const int gqx = qi & 7;
            const int lr  = (qi >> 3) + dy;
            const int col = gqx + dx;
            const int kyg = y0 + gqy - HALO + dy;
            const int kxg = x0 + gqx - HALO + dx;
            float v = 0.f;
            if ((unsigned)kyg < (unsigned)H_ && (unsigned)kxg < (unsigned)W_)
                v = sh.sS[pp2][qi * SROW + lr * 17 + col] * scale;
            out[((size_t)b * NDISP + d) * PLANE + (size_t)(y0 + gqy) * W_ + (x0 + gqx)] = v;
        }
    }
}

extern "C" void kernel_launch(void* const* d_in, const int* in_sizes, int n_in,
                              void* d_out, int out_size, void* d_ws, size_t ws_size,
                              hipStream_t stream) {
    const float* first  = (const float*)d_in[0];
    const float* second = (const float*)d_in[1];
    float* out = (float*)d_out;

    dim3 grid(1024);
    dim3 block(256);
    corr_mfma<<<grid, block, 0, stream>>>(first, second, out);
}